// Round 4
// baseline (904.756 us; speedup 1.0000x reference)
//
#include <hip/hip_runtime.h>
#include <cstdint>
#include <cstddef>

#define NN 100000
#define NE 3200000
#define D 128

typedef __attribute__((ext_vector_type(8))) short bf16x8;
typedef __attribute__((ext_vector_type(4))) float f32x4;

__device__ __forceinline__ unsigned short f2bf(float f) {
    unsigned int u = __float_as_uint(f);
    u += 0x7FFFu + ((u >> 16) & 1u);          // round-to-nearest-even
    return (unsigned short)(u >> 16);
}
__device__ __forceinline__ float bflo(unsigned int v) { return __uint_as_float(v << 16); }
__device__ __forceinline__ float bfhi(unsigned int v) { return __uint_as_float(v & 0xFFFF0000u); }

// ---------------------------------------------------------------------------
// x (fp32) -> x_bf16.  12.8M elems, 8 per thread.
// ---------------------------------------------------------------------------
__global__ __launch_bounds__(256)
void k_convert(const float* __restrict__ x, unsigned short* __restrict__ xb)
{
    const size_t i8 = ((size_t)blockIdx.x * 256 + threadIdx.x) * 8;
    const float4 v0 = *reinterpret_cast<const float4*>(x + i8);
    const float4 v1 = *reinterpret_cast<const float4*>(x + i8 + 4);
    uint4 o;
    o.x = (unsigned)f2bf(v0.x) | ((unsigned)f2bf(v0.y) << 16);
    o.y = (unsigned)f2bf(v0.z) | ((unsigned)f2bf(v0.w) << 16);
    o.z = (unsigned)f2bf(v1.x) | ((unsigned)f2bf(v1.y) << 16);
    o.w = (unsigned)f2bf(v1.z) | ((unsigned)f2bf(v1.w) << 16);
    *reinterpret_cast<uint4*>(xb + i8) = o;
}

// ---------------------------------------------------------------------------
// CSR pass 1: degree count. 4 edges/thread, reads dst half only.
// ---------------------------------------------------------------------------
__global__ __launch_bounds__(256)
void k_count(const int* __restrict__ ei, unsigned int* __restrict__ deg)
{
    const int e0 = (blockIdx.x * 256 + threadIdx.x) * 4;
    const int4 d4 = *reinterpret_cast<const int4*>(ei + NE + e0);
    atomicAdd(deg + d4.x, 1u);
    atomicAdd(deg + d4.y, 1u);
    atomicAdd(deg + d4.z, 1u);
    atomicAdd(deg + d4.w, 1u);
}

// ---------------------------------------------------------------------------
// CSR pass 2: exclusive scan of deg -> offsets, plus cursor copy.
// Single block, 1024 threads, 98 items each (1024*98 >= NN).
// ---------------------------------------------------------------------------
__global__ __launch_bounds__(1024)
void k_scan(const unsigned int* __restrict__ deg,
            unsigned int* __restrict__ offsets,
            unsigned int* __restrict__ cursor)
{
    __shared__ unsigned int part[1024];
    const int t = threadIdx.x;
    const int base = t * 98;
    unsigned int s = 0;
    for (int i = 0; i < 98; ++i) {
        const int idx = base + i;
        if (idx < NN) s += deg[idx];
    }
    part[t] = s;
    __syncthreads();
    for (int d = 1; d < 1024; d <<= 1) {
        const unsigned int v = (t >= d) ? part[t - d] : 0u;
        __syncthreads();
        part[t] += v;
        __syncthreads();
    }
    unsigned int run = (t == 0) ? 0u : part[t - 1];
    for (int i = 0; i < 98; ++i) {
        const int idx = base + i;
        if (idx < NN) {
            offsets[idx] = run;
            cursor[idx]  = run;
            run += deg[idx];
        }
    }
}

// ---------------------------------------------------------------------------
// CSR pass 3: scatter src ids into adj (12.8 MB footprint, L2/L3-resident).
// ---------------------------------------------------------------------------
__global__ __launch_bounds__(256)
void k_scatter(const int* __restrict__ ei, unsigned int* __restrict__ cursor,
               int* __restrict__ adj)
{
    const int e0 = (blockIdx.x * 256 + threadIdx.x) * 4;
    const int4 s4 = *reinterpret_cast<const int4*>(ei + e0);
    const int4 d4 = *reinterpret_cast<const int4*>(ei + NE + e0);
    #pragma unroll
    for (int j = 0; j < 4; ++j) {
        const int src = (&s4.x)[j];
        const int dst = (&d4.x)[j];
        const unsigned int pos = atomicAdd(cursor + dst, 1u);
        adj[pos] = src;
    }
}

// ---------------------------------------------------------------------------
// Pack W' = [Wl; Wr] (256x128) into bf16 MFMA B-fragment layout:
// wf[((kt*8 + t)*64 + lane)*8 + j] = W'[kt*32 + (lane>>4)*8 + j][t*16 + (lane&15)]
// so each wave reads one 16B chunk per (kt, tile).
// ---------------------------------------------------------------------------
__global__ __launch_bounds__(256)
void k_wprep(const float* __restrict__ Wl, const float* __restrict__ Wr,
             unsigned short* __restrict__ wf)
{
    const int tid  = blockIdx.x * 256 + threadIdx.x;   // 32768 total
    const int j    = tid & 7;
    const int lane = (tid >> 3) & 63;
    const int t    = (tid >> 9) & 7;
    const int kt   = tid >> 12;
    const int k    = kt * 32 + (lane >> 4) * 8 + j;
    const int c    = t * 16 + (lane & 15);
    const float v  = (k < D) ? Wl[k * D + c] : Wr[(k - D) * D + c];
    wf[tid] = f2bf(v);
}

// ---------------------------------------------------------------------------
// Fused: gather-mean (bf16, into LDS) -> MFMA GEMM [mean|x] @ [Wl;Wr] + b
// -> LayerNorm -> exact GELU -> store.
// Block = 256 thr = 4 waves; wave w owns 16 nodes. LDS = 64 x 136 shorts
// (~17.4 KB, row stride 272B -> ~2-way bank aliasing on ds_read_b128, free).
// A-frag layout: row = lane&15, k = (lane>>4)*8 + j (guide §3, m89-verified
// C/D: col = lane&15, row = (lane>>4)*4 + reg).
// ---------------------------------------------------------------------------
__global__ __launch_bounds__(256, 4)
void k_fused(const unsigned short* __restrict__ xb,
             const unsigned int* __restrict__ deg,
             const unsigned int* __restrict__ offsets,
             const int* __restrict__ adj,
             const unsigned short* __restrict__ wf,
             const float* __restrict__ bl,
             const float* __restrict__ gamma,
             const float* __restrict__ beta,
             float* __restrict__ out)
{
    __shared__ unsigned short smean[64][136];

    const int t    = threadIdx.x;
    const int w    = t >> 6;
    const int lane = t & 63;
    const int nodeBase = blockIdx.x * 64;

    // ---- phase 1: gather mean for this wave's 16 nodes ----
    for (int i = 0; i < 16; ++i) {
        const int node = nodeBase + w * 16 + i;
        float ax = 0.f, ay = 0.f;
        int dg = 0; unsigned int off = 0;
        if (node < NN) { dg = (int)deg[node]; off = offsets[node]; }
        int c = 0;
        for (; c + 4 <= dg; c += 4) {
            const int n0 = adj[off + c + 0];
            const int n1 = adj[off + c + 1];
            const int n2 = adj[off + c + 2];
            const int n3 = adj[off + c + 3];
            const unsigned int v0 = *reinterpret_cast<const unsigned int*>(xb + ((size_t)n0 << 7) + (lane << 1));
            const unsigned int v1 = *reinterpret_cast<const unsigned int*>(xb + ((size_t)n1 << 7) + (lane << 1));
            const unsigned int v2 = *reinterpret_cast<const unsigned int*>(xb + ((size_t)n2 << 7) + (lane << 1));
            const unsigned int v3 = *reinterpret_cast<const unsigned int*>(xb + ((size_t)n3 << 7) + (lane << 1));
            ax += bflo(v0) + bflo(v1) + bflo(v2) + bflo(v3);
            ay += bfhi(v0) + bfhi(v1) + bfhi(v2) + bfhi(v3);
        }
        for (; c < dg; ++c) {
            const int n0 = adj[off + c];
            const unsigned int v0 = *reinterpret_cast<const unsigned int*>(xb + ((size_t)n0 << 7) + (lane << 1));
            ax += bflo(v0); ay += bfhi(v0);
        }
        const float inv = 1.0f / (float)(dg > 1 ? dg : 1);
        const unsigned int packed = (node < NN)
            ? ((unsigned)f2bf(ax * inv) | ((unsigned)f2bf(ay * inv) << 16)) : 0u;
        *reinterpret_cast<unsigned int*>(&smean[w * 16 + i][lane << 1]) = packed;
    }
    __syncthreads();

    // ---- phase 2: MFMA GEMM, K = 256 = [mean(128) | x(128)] ----
    const int row  = lane & 15;      // A row / C col selector
    const int kgrp = lane >> 4;      // 0..3
    const int node_r = nodeBase + w * 16 + row;
    const size_t xrow = (size_t)(node_r < NN ? node_r : NN - 1) << 7;

    f32x4 acc[8];
    const f32x4 zero = {0.f, 0.f, 0.f, 0.f};
    #pragma unroll
    for (int q = 0; q < 8; ++q) acc[q] = zero;

    #pragma unroll
    for (int kt = 0; kt < 8; ++kt) {
        bf16x8 a;
        if (kt < 4) {
            a = *reinterpret_cast<const bf16x8*>(&smean[w * 16 + row][kt * 32 + kgrp * 8]);
        } else {
            a = *reinterpret_cast<const bf16x8*>(xb + xrow + (kt - 4) * 32 + kgrp * 8);
        }
        #pragma unroll
        for (int q = 0; q < 8; ++q) {
            const bf16x8 b = *reinterpret_cast<const bf16x8*>(wf + (((kt * 8 + q) * 64 + lane) << 3));
            acc[q] = __builtin_amdgcn_mfma_f32_16x16x32_bf16(a, b, acc[q], 0, 0, 0);
        }
    }

    // ---- phase 3: bias + LayerNorm + exact GELU + store ----
    const int col = lane & 15;
    float gv[8], bev[8], blv[8];
    #pragma unroll
    for (int q = 0; q < 8; ++q) {
        gv[q]  = gamma[q * 16 + col];
        bev[q] = beta[q * 16 + col];
        blv[q] = bl[q * 16 + col];
    }
    const float k2 = 0.70710678118654752f;
    #pragma unroll
    for (int r = 0; r < 4; ++r) {
        float p = 0.f, p2 = 0.f;
        #pragma unroll
        for (int q = 0; q < 8; ++q) {
            const float h = acc[q][r] + blv[q];
            p += h; p2 += h * h;
        }
        #pragma unroll
        for (int m = 1; m <= 8; m <<= 1) {
            p  += __shfl_xor(p,  m, 64);
            p2 += __shfl_xor(p2, m, 64);
        }
        const float mu   = p * (1.0f / 128.0f);
        const float var  = p2 * (1.0f / 128.0f) - mu * mu;
        const float rstd = rsqrtf(var + 1e-5f);
        const int node = nodeBase + w * 16 + kgrp * 4 + r;
        if (node < NN) {
            #pragma unroll
            for (int q = 0; q < 8; ++q) {
                const float h = acc[q][r] + blv[q];
                const float y = (h - mu) * rstd * gv[q] + bev[q];
                out[(size_t)node * D + q * 16 + col] = 0.5f * y * (1.0f + erff(y * k2));
            }
        }
    }
}

extern "C" void kernel_launch(void* const* d_in, const int* in_sizes, int n_in,
                              void* d_out, int out_size, void* d_ws, size_t ws_size,
                              hipStream_t stream)
{
    const float* x     = (const float*)d_in[0];
    const int*   ei    = (const int*)d_in[1];
    const float* Wl    = (const float*)d_in[2];
    const float* bl    = (const float*)d_in[3];
    const float* Wr    = (const float*)d_in[4];
    const float* gamma = (const float*)d_in[5];
    const float* beta  = (const float*)d_in[6];
    float* out = (float*)d_out;

    // ws layout (total ~40.0 MB; 51.6 MB proven available in round 1)
    char* w = (char*)d_ws;
    unsigned int* deg     = (unsigned int*)(w + 0);              // 400 KB
    unsigned int* offsets = (unsigned int*)(w + 524288);         // 400 KB
    unsigned int* cursor  = (unsigned int*)(w + 1048576);        // 400 KB
    int*          adj     = (int*)(w + 1572864);                 // 12.8 MB
    unsigned short* xb    = (unsigned short*)(w + 14372864);     // 25.6 MB
    unsigned short* wf    = (unsigned short*)(w + 39972864);     // 64 KB

    hipMemsetAsync(deg, 0, (size_t)NN * sizeof(unsigned int), stream);

    k_convert<<<6250, 256, 0, stream>>>(x, xb);                  // NN*D/8/256
    k_count<<<NE / 1024, 256, 0, stream>>>(ei, deg);
    k_scan<<<1, 1024, 0, stream>>>(deg, offsets, cursor);
    k_scatter<<<NE / 1024, 256, 0, stream>>>(ei, cursor, adj);
    k_wprep<<<128, 256, 0, stream>>>(Wl, Wr, wf);                // 32768/256
    k_fused<<<(NN + 63) / 64, 256, 0, stream>>>(xb, deg, offsets, adj, wf,
                                                bl, gamma, beta, out);
}